// Round 9
// baseline (533.827 us; speedup 1.0000x reference)
//
#include <hip/hip_runtime.h>
#include <math.h>
#include <float.h>

// TopK router: logits = x(N,2048) @ W(64,2048)^T, softmax, top-2, renorm.
// Output: [weights 2N floats][indices 2N floats]
//
// R7 post-mortem: MI=1/EI=4 was LDS-BW-bound (4 B/FMA -> 8.6 GB LDS -> ~124us).
// R8: 64-lane expert split (EI=1), MI=4 tokens/thread:
//   - 1024 blocks x 256 = 4 blocks/CU (41% occ) AND 1 B/FMA LDS traffic.
//   - W tile [64][128] XOR-swizzled 16B granules (g ^ (row&7)): wave64 b128
//     read of 64 expert rows spreads over all 32 banks (structural min).
//   - x loads are wave-broadcast (same addr all lanes) = 1 cacheline/instr.
//   - A/B double-buffer prefetch of x,W frags; full-wave top-2 butterfly.

#define TK_D 2048
#define TK_E 64
#define TK_BK 128
#define TK_NKT (TK_D / TK_BK)
#define TK_MI 4
#define TK_BM 16   // 4 waves * 4 tokens

__global__ __launch_bounds__(256, 4)
void topk_router_kernel(const float* __restrict__ x,
                        const float* __restrict__ W,
                        float* __restrict__ out, int N) {
    __shared__ float wlds[TK_E * TK_BK];   // 32 KB, swizzled granules

    const int tid  = threadIdx.x;
    const int e    = tid & 63;     // expert lane
    const int slot = tid >> 6;     // wave 0..3
    const int swz  = e & 7;
    const int base = blockIdx.x * TK_BM;

    const float* xrow[TK_MI];
#pragma unroll
    for (int mi = 0; mi < TK_MI; ++mi)
        xrow[mi] = x + (size_t)(base + slot * TK_MI + mi) * TK_D;

    float acc[TK_MI] = {0.f, 0.f, 0.f, 0.f};
    const float* wbase = wlds + e * TK_BK;

    for (int kt = 0; kt < TK_NKT; ++kt) {
        __syncthreads();
        // stage W[0..63][kt*128 .. +128): 2048 float4, 8/thread, swizzled dst
#pragma unroll
        for (int j = 0; j < 8; ++j) {
            int s = tid + 256 * j;
            int row = s >> 5, g = s & 31;
            float4 v = *(const float4*)(W + (size_t)row * TK_D + kt * TK_BK + g * 4);
            *(float4*)&wlds[(row * 32 + (g ^ (row & 7))) * 4] = v;
        }
        __syncthreads();

        const int koff = kt * TK_BK;
        float4 xa[TK_MI], xb[TK_MI], wa, wb;
        // prologue: load slot A with kk=0
        wa = *(const float4*)(wbase + ((0 ^ swz) << 2));
#pragma unroll
        for (int mi = 0; mi < TK_MI; ++mi)
            xa[mi] = *(const float4*)(xrow[mi] + koff);

#pragma unroll 3
        for (int kk = 0; kk < 30; kk += 2) {
            // load B(kk+1), compute A(kk)
            wb = *(const float4*)(wbase + (((kk + 1) ^ swz) << 2));
#pragma unroll
            for (int mi = 0; mi < TK_MI; ++mi)
                xb[mi] = *(const float4*)(xrow[mi] + koff + (kk + 1) * 4);
#pragma unroll
            for (int mi = 0; mi < TK_MI; ++mi) {
                acc[mi] = fmaf(xa[mi].x, wa.x, acc[mi]);
                acc[mi] = fmaf(xa[mi].y, wa.y, acc[mi]);
                acc[mi] = fmaf(xa[mi].z, wa.z, acc[mi]);
                acc[mi] = fmaf(xa[mi].w, wa.w, acc[mi]);
            }
            // load A(kk+2), compute B(kk+1)
            wa = *(const float4*)(wbase + (((kk + 2) ^ swz) << 2));
#pragma unroll
            for (int mi = 0; mi < TK_MI; ++mi)
                xa[mi] = *(const float4*)(xrow[mi] + koff + (kk + 2) * 4);
#pragma unroll
            for (int mi = 0; mi < TK_MI; ++mi) {
                acc[mi] = fmaf(xb[mi].x, wb.x, acc[mi]);
                acc[mi] = fmaf(xb[mi].y, wb.y, acc[mi]);
                acc[mi] = fmaf(xb[mi].z, wb.z, acc[mi]);
                acc[mi] = fmaf(xb[mi].w, wb.w, acc[mi]);
            }
        }
        // tail: A holds kk=30; load B(31), compute A(30), compute B(31)
        wb = *(const float4*)(wbase + ((31 ^ swz) << 2));
#pragma unroll
        for (int mi = 0; mi < TK_MI; ++mi)
            xb[mi] = *(const float4*)(xrow[mi] + koff + 31 * 4);
#pragma unroll
        for (int mi = 0; mi < TK_MI; ++mi) {
            acc[mi] = fmaf(xa[mi].x, wa.x, acc[mi]);
            acc[mi] = fmaf(xa[mi].y, wa.y, acc[mi]);
            acc[mi] = fmaf(xa[mi].z, wa.z, acc[mi]);
            acc[mi] = fmaf(xa[mi].w, wa.w, acc[mi]);
        }
#pragma unroll
        for (int mi = 0; mi < TK_MI; ++mi) {
            acc[mi] = fmaf(xb[mi].x, wb.x, acc[mi]);
            acc[mi] = fmaf(xb[mi].y, wb.y, acc[mi]);
            acc[mi] = fmaf(xb[mi].z, wb.z, acc[mi]);
            acc[mi] = fmaf(xb[mi].w, wb.w, acc[mi]);
        }
    }

    float* outw = out;
    float* outi = out + 2 * (size_t)N;

    // Full-wave epilogue: 64 experts live on 64 lanes. 6-stage butterfly
    // top-2 merge (jax tie: lower index wins), then 6-stage exp-sum.
#pragma unroll
    for (int mi = 0; mi < TK_MI; ++mi) {
        float v  = acc[mi];
        float v1 = v, v2 = -FLT_MAX;
        int   i1 = e, i2 = e;
#pragma unroll
        for (int xm = 1; xm <= 32; xm <<= 1) {
            float ov1 = __shfl_xor(v1, xm);
            int   oi1 = __shfl_xor(i1, xm);
            float ov2 = __shfl_xor(v2, xm);
            int   oi2 = __shfl_xor(i2, xm);
            bool owin = (ov1 > v1) || (ov1 == v1 && oi1 < i1);
            if (owin) {
                bool sw = (v1 > ov2) || (v1 == ov2 && i1 < oi2);
                v2 = sw ? v1 : ov2; i2 = sw ? i1 : oi2;
                v1 = ov1; i1 = oi1;
            } else {
                bool sw = (ov1 > v2) || (ov1 == v2 && oi1 < i2);
                v2 = sw ? ov1 : v2; i2 = sw ? oi1 : i2;
            }
        }
        float s = expf(v - v1);
#pragma unroll
        for (int xm = 1; xm <= 32; xm <<= 1)
            s += __shfl_xor(s, xm);

        if (e == mi) {   // lanes 0..3 each write one token
            int token = base + slot * TK_MI + mi;
            float p1 = 1.0f / s;
            float p2 = expf(v2 - v1) / s;
            float dn = p1 + p2 + 1e-9f;
            *(float2*)&outw[2 * (size_t)token] = make_float2(p1 / dn, p2 / dn);
            *(float2*)&outi[2 * (size_t)token] = make_float2((float)i1, (float)i2);
        }
    }
}

extern "C" void kernel_launch(void* const* d_in, const int* in_sizes, int n_in,
                              void* d_out, int out_size, void* d_ws, size_t ws_size,
                              hipStream_t stream) {
    const float* x = (const float*)d_in[0];
    const float* W = (const float*)d_in[1];
    float* out = (float*)d_out;
    int N = in_sizes[0] / TK_D;     // 16384
    int grid = N / TK_BM;           // 1024 blocks, 4 per CU
    topk_router_kernel<<<grid, 256, 0, stream>>>(x, W, out, N);
}

// Round 10
// 290.607 us; speedup vs baseline: 1.8369x; 1.8369x over previous
//
#include <hip/hip_runtime.h>
#include <math.h>
#include <float.h>

// TopK router: logits = x(N,2048) @ W(64,2048)^T, softmax, top-2, renorm.
// Output: [weights 2N floats][indices 2N floats]
//
// R9 post-mortem: A/B dbuf arrays spilled (WRITE 42MB = 160B/thread) -> 406us.
// R10: split-K two-phase.
//  Phase 1: R3's proven spill-free inner loop (MI=4,EI=4, 16-lane e-split,
//    1 B/FMA LDS), each block does D/4=512 k-range -> 1024 blocks = 4/CU
//    (41% occ, measured R7/R9). Partials -> ws[kc][token][e] (16.8 MB).
//  Phase 2: wave/token, lane/expert: sum 4 partials, R9-proven butterfly
//    top-2 + softmax + renorm.

#define TK_D 2048
#define TK_E 64
#define TK_SPLIT 4
#define TK_DC (TK_D / TK_SPLIT)   // 512
#define TK_BK 128
#define TK_NKT (TK_DC / TK_BK)    // 4
#define TK_MI 4
#define TK_EI 4
#define TK_BM 64                  // tokens per block

__global__ __launch_bounds__(256, 4)
void topk_part_kernel(const float* __restrict__ x,
                      const float* __restrict__ W,
                      float* __restrict__ part, int N) {
    // +4 float pad: 2-way bank aliasing only (free per m136)
    __shared__ float wlds[TK_E][TK_BK + 4];

    const int tid = threadIdx.x;
    const int eg  = tid & 15;          // expert lane (0..15)
    const int mg  = tid >> 4;          // token slot (0..15)
    const int tb  = blockIdx.x >> 2;   // token block
    const int kc  = blockIdx.x & 3;    // k-chunk
    const int base = tb * TK_BM;
    const size_t koff0 = (size_t)kc * TK_DC;

    const float* xr[TK_MI];
#pragma unroll
    for (int mi = 0; mi < TK_MI; ++mi)
        xr[mi] = x + (size_t)(base + mg + 16 * mi) * TK_D + koff0;

    float acc[TK_MI][TK_EI];
#pragma unroll
    for (int mi = 0; mi < TK_MI; ++mi)
#pragma unroll
        for (int ei = 0; ei < TK_EI; ++ei) acc[mi][ei] = 0.f;

    for (int kt = 0; kt < TK_NKT; ++kt) {
        __syncthreads();
        // stage W[0..63][koff0 + kt*128 .. +128): 2048 float4, 8 per thread
#pragma unroll
        for (int j = 0; j < 8; ++j) {
            int s   = tid + 256 * j;
            int row = s >> 5;
            int c4  = s & 31;
            float4 v = *(const float4*)(W + (size_t)row * TK_D + koff0 + kt * TK_BK + c4 * 4);
            *(float4*)&wlds[row][c4 * 4] = v;
        }
        __syncthreads();

#pragma unroll 8
        for (int kk = 0; kk < TK_BK / 4; ++kk) {
            float4 xv[TK_MI], wv[TK_EI];
#pragma unroll
            for (int mi = 0; mi < TK_MI; ++mi)
                xv[mi] = *(const float4*)(xr[mi] + kt * TK_BK + kk * 4);
#pragma unroll
            for (int ei = 0; ei < TK_EI; ++ei)
                wv[ei] = *(const float4*)&wlds[eg + 16 * ei][kk * 4];
#pragma unroll
            for (int mi = 0; mi < TK_MI; ++mi)
#pragma unroll
                for (int ei = 0; ei < TK_EI; ++ei) {
                    acc[mi][ei] = fmaf(xv[mi].x, wv[ei].x, acc[mi][ei]);
                    acc[mi][ei] = fmaf(xv[mi].y, wv[ei].y, acc[mi][ei]);
                    acc[mi][ei] = fmaf(xv[mi].z, wv[ei].z, acc[mi][ei]);
                    acc[mi][ei] = fmaf(xv[mi].w, wv[ei].w, acc[mi][ei]);
                }
        }
    }

    // write partials: part[(kc*N + token)*64 + e]; per (mi,ei) wave-store =
    // 4 chunks of 64 contiguous bytes (eg across lanes) -> coalesced.
#pragma unroll
    for (int mi = 0; mi < TK_MI; ++mi) {
        int token = base + mg + 16 * mi;
        float* p = part + ((size_t)kc * N + token) * TK_E + eg;
#pragma unroll
        for (int ei = 0; ei < TK_EI; ++ei)
            p[16 * ei] = acc[mi][ei];
    }
}

__global__ __launch_bounds__(256, 8)
void topk_final_kernel(const float* __restrict__ part,
                       float* __restrict__ out, int N) {
    const int tok = blockIdx.x * 4 + (threadIdx.x >> 6);  // wave per token
    const int e   = threadIdx.x & 63;                     // lane per expert

    const float* p = part + (size_t)tok * TK_E + e;
    float v = p[0];
    v += p[(size_t)1 * N * TK_E];
    v += p[(size_t)2 * N * TK_E];
    v += p[(size_t)3 * N * TK_E];

    // 6-stage butterfly top-2 (jax tie: lower index wins) — proven in R9.
    float v1 = v, v2 = -FLT_MAX;
    int   i1 = e, i2 = e;
#pragma unroll
    for (int xm = 1; xm <= 32; xm <<= 1) {
        float ov1 = __shfl_xor(v1, xm);
        int   oi1 = __shfl_xor(i1, xm);
        float ov2 = __shfl_xor(v2, xm);
        int   oi2 = __shfl_xor(i2, xm);
        bool owin = (ov1 > v1) || (ov1 == v1 && oi1 < i1);
        if (owin) {
            bool sw = (v1 > ov2) || (v1 == ov2 && i1 < oi2);
            v2 = sw ? v1 : ov2; i2 = sw ? i1 : oi2;
            v1 = ov1; i1 = oi1;
        } else {
            bool sw = (ov1 > v2) || (ov1 == v2 && oi1 < i2);
            v2 = sw ? ov1 : v2; i2 = sw ? oi1 : i2;
        }
    }
    float s = expf(v - v1);
#pragma unroll
    for (int xm = 1; xm <= 32; xm <<= 1)
        s += __shfl_xor(s, xm);

    if (e == 0) {
        float p1 = 1.0f / s;
        float p2 = expf(v2 - v1) / s;
        float dn = p1 + p2 + 1e-9f;
        *(float2*)&out[2 * (size_t)tok] = make_float2(p1 / dn, p2 / dn);
        *(float2*)&out[2 * ((size_t)N + tok)] = make_float2((float)i1, (float)i2);
    }
}

extern "C" void kernel_launch(void* const* d_in, const int* in_sizes, int n_in,
                              void* d_out, int out_size, void* d_ws, size_t ws_size,
                              hipStream_t stream) {
    const float* x = (const float*)d_in[0];
    const float* W = (const float*)d_in[1];
    float* out  = (float*)d_out;
    float* part = (float*)d_ws;           // needs 4*N*64*4 B = 16.8 MB
    int N = in_sizes[0] / TK_D;           // 16384

    int grid1 = (N / TK_BM) * TK_SPLIT;   // 1024 blocks, 4 per CU
    topk_part_kernel<<<grid1, 256, 0, stream>>>(x, W, part, N);

    int grid2 = N / 4;                    // wave per token
    topk_final_kernel<<<grid2, 256, 0, stream>>>(part, out, N);
}

// Round 14
// 220.187 us; speedup vs baseline: 2.4244x; 1.3198x over previous
//
#include <hip/hip_runtime.h>
#include <math.h>
#include <float.h>

// TopK router: logits = x(N,2048) @ W(64,2048)^T, softmax, top-2, renorm.
// Output: [weights 2N floats][indices 2N floats]
//
// R10 post-mortem: occupancy 11->41% left VALUBusy at 28% -> per-kk global
// x-load latency exposed (no pipelining at VGPR=64; 256 x-streams/CU thrash
// 32KB L1). R11: stage BOTH x and W tiles via global_load_lds (async, no
// VGPR round-trip); inner loop is pure LDS->FMA. Granule-XOR swizzle
// L(row,g)=row*16+(g^(row&7)) applied via pre-swizzled GLOBAL source
// (linear LDS dest, required by gload_lds) + XOR on read.
//  - W-read: rows eg+16ei, fixed kk -> bank-groups (kk^row)&7: 2-way (free)
//  - x-read: rows mg+16mi, 4 rows/wave -> distinct groups, conflict-free
// Phase 2 unchanged (R10: absmax 0.0).

#define TK_D 2048
#define TK_E 64
#define TK_SPLIT 4
#define TK_DC (TK_D / TK_SPLIT)   // 512
#define TK_BK 64
#define TK_NKT (TK_DC / TK_BK)    // 8
#define TK_MI 4
#define TK_EI 4
#define TK_BM 64

__global__ __launch_bounds__(256, 4)
void topk_part_kernel(const float* __restrict__ x,
                      const float* __restrict__ W,
                      float* __restrict__ part, int N) {
    __shared__ float wtile[TK_E * TK_BK];    // 16 KB, swizzled granules
    __shared__ float xtile[TK_BM * TK_BK];   // 16 KB, swizzled granules

    const int tid  = threadIdx.x;
    const int eg   = tid & 15;          // expert lane (0..15)
    const int mg   = tid >> 4;          // token slot (0..15)
    const int wvid = tid >> 6;          // wave 0..3
    const int lane = tid & 63;
    const int tb   = blockIdx.x >> 2;   // token block
    const int kc   = blockIdx.x & 3;    // k-chunk
    const int base = tb * TK_BM;
    const size_t koff0 = (size_t)kc * TK_DC;

    // staging geometry (chunk = 1 KB = 4 rows; 16 chunks per tile, 4/wave)
    const int srow = (lane >> 4);       // row within chunk quad
    const int sgp  = lane & 15;         // linear granule within row

    float acc[TK_MI][TK_EI];
#pragma unroll
    for (int mi = 0; mi < TK_MI; ++mi)
#pragma unroll
        for (int ei = 0; ei < TK_EI; ++ei) acc[mi][ei] = 0.f;

    for (int kt = 0; kt < TK_NKT; ++kt) {
        __syncthreads();                 // prev-kt reads done before overwrite
        const size_t kbase = koff0 + (size_t)kt * TK_BK;
#pragma unroll
        for (int j = 0; j < 4; ++j) {
            int c   = wvid + 4 * j;          // chunk 0..15
            int row = 4 * c + srow;
            int g   = sgp ^ (row & 7);       // pre-swizzled source granule
            const float* gw = W + (size_t)row * TK_D + kbase + g * 4;
            const float* gx = x + (size_t)(base + row) * TK_D + kbase + g * 4;
#if __has_builtin(__builtin_amdgcn_global_load_lds)
            __builtin_amdgcn_global_load_lds(
                (const __attribute__((address_space(1))) void*)gw,
                (__attribute__((address_space(3))) void*)&wtile[c * 256], 16, 0, 0);
            __builtin_amdgcn_global_load_lds(
                (const __attribute__((address_space(1))) void*)gx,
                (__attribute__((address_space(3))) void*)&xtile[c * 256], 16, 0, 0);
#else
            *(float4*)&wtile[c * 256 + lane * 4] = *(const float4*)gw;
            *(float4*)&xtile[c * 256 + lane * 4] = *(const float4*)gx;
#endif
        }
        __syncthreads();                 // barrier drain waits vmcnt(0)

#pragma unroll
        for (int kk = 0; kk < TK_BK / 4; ++kk) {
            float4 wv[TK_EI], xv[TK_MI];
#pragma unroll
            for (int ei = 0; ei < TK_EI; ++ei) {
                int row = eg + 16 * ei;
                wv[ei] = *(const float4*)&wtile[(row * 16 + (kk ^ (row & 7))) * 4];
            }
#pragma unroll
            for (int mi = 0; mi < TK_MI; ++mi) {
                int row = mg + 16 * mi;
                xv[mi] = *(const float4*)&xtile[(row * 16 + (kk ^ (row & 7))) * 4];
            }
#pragma unroll
            for (int mi = 0; mi < TK_MI; ++mi)
#pragma unroll
                for (int ei = 0; ei < TK_EI; ++ei) {
                    acc[mi][ei] = fmaf(xv[mi].x, wv[ei].x, acc[mi][ei]);
                    acc[mi][ei] = fmaf(xv[mi].y, wv[ei].y, acc[mi][ei]);
                    acc[mi][ei] = fmaf(xv[mi].z, wv[ei].z, acc[mi][ei]);
                    acc[mi][ei] = fmaf(xv[mi].w, wv[ei].w, acc[mi][ei]);
                }
        }
    }

    // write partials: part[(kc*N + token)*64 + e] (R10-proven)
#pragma unroll
    for (int mi = 0; mi < TK_MI; ++mi) {
        int token = base + mg + 16 * mi;
        float* p = part + ((size_t)kc * N + token) * TK_E + eg;
#pragma unroll
        for (int ei = 0; ei < TK_EI; ++ei)
            p[16 * ei] = acc[mi][ei];
    }
}

__global__ __launch_bounds__(256, 8)
void topk_final_kernel(const float* __restrict__ part,
                       float* __restrict__ out, int N) {
    const int tok = blockIdx.x * 4 + (threadIdx.x >> 6);  // wave per token
    const int e   = threadIdx.x & 63;                     // lane per expert

    const float* p = part + (size_t)tok * TK_E + e;
    float v = p[0];
    v += p[(size_t)1 * N * TK_E];
    v += p[(size_t)2 * N * TK_E];
    v += p[(size_t)3 * N * TK_E];

    // 6-stage butterfly top-2 (jax tie: lower index wins) — proven R9/R10.
    float v1 = v, v2 = -FLT_MAX;
    int   i1 = e, i2 = e;
#pragma unroll
    for (int xm = 1; xm <= 32; xm <<= 1) {
        float ov1 = __shfl_xor(v1, xm);
        int   oi1 = __shfl_xor(i1, xm);
        float ov2 = __shfl_xor(v2, xm);
        int   oi2 = __shfl_xor(i2, xm);
        bool owin = (ov1 > v1) || (ov1 == v1 && oi1 < i1);
        if (owin) {
            bool sw = (v1 > ov2) || (v1 == ov2 && i1 < oi2);
            v2 = sw ? v1 : ov2; i2 = sw ? i1 : oi2;
            v1 = ov1; i1 = oi1;
        } else {
            bool sw = (ov1 > v2) || (ov1 == v2 && oi1 < i2);
            v2 = sw ? ov1 : v2; i2 = sw ? oi1 : i2;
        }
    }
    float s = expf(v - v1);
#pragma unroll
    for (int xm = 1; xm <= 32; xm <<= 1)
        s += __shfl_xor(s, xm);

    if (e == 0) {
        float p1 = 1.0f / s;
        float p2 = expf(v2 - v1) / s;
        float dn = p1 + p2 + 1e-9f;
        *(float2*)&out[2 * (size_t)tok] = make_float2(p1 / dn, p2 / dn);
        *(float2*)&out[2 * ((size_t)N + tok)] = make_float2((float)i1, (float)i2);
    }
}

extern "C" void kernel_launch(void* const* d_in, const int* in_sizes, int n_in,
                              void* d_out, int out_size, void* d_ws, size_t ws_size,
                              hipStream_t stream) {
    const float* x = (const float*)d_in[0];
    const float* W = (const float*)d_in[1];
    float* out  = (float*)d_out;
    float* part = (float*)d_ws;           // 4*N*64*4 B = 16.8 MB
    int N = in_sizes[0] / TK_D;           // 16384

    int grid1 = (N / TK_BM) * TK_SPLIT;   // 1024 blocks, 4 per CU
    topk_part_kernel<<<grid1, 256, 0, stream>>>(x, W, part, N);

    int grid2 = N / 4;                    // wave per token
    topk_final_kernel<<<grid2, 256, 0, stream>>>(part, out, N);
}